// Round 3
// baseline (431.333 us; speedup 1.0000x reference)
//
#include <hip/hip_runtime.h>

#define S 2048
#define Dh 64
#define NH 16
#define SD (S*Dh)                 // 131072 elements per head plane
#define SSZ ((size_t)S*(size_t)S) // attention matrix elements per head

typedef __attribute__((ext_vector_type(4))) float f32x4;
typedef __attribute__((ext_vector_type(8))) short s16x8;

// workspace layout (byte offsets)
#define WSB_QSUM 0                          // 1024 f32 (4 KB)
#define WSB_RINV 4096                       // 16*2048 f32 (128 KB)
#define WSB_MASK 135168                     // 65536 uint64 bitmask (512 KB)
#define WSB_QS   659456                     // NH*SD bf16 (4 MB)
#define WSB_KS   (WSB_QS + 4194304)
#define WSB_VT   (WSB_KS + 4194304)         // ends ~12.6 MB

__device__ __forceinline__ ushort f2bf(float x) {
    unsigned u = __builtin_bit_cast(unsigned, x);
    u = (u + 0x7fffu + ((u >> 16) & 1u)) >> 16;
    return (ushort)u;
}

// ---- Q column-softmax denominators: sum_s exp(q[h,s,d]) per (head,d) ------
__global__ void k_qsum(const float* __restrict__ q, float* __restrict__ qsum) {
    const int head  = blockIdx.x >> 3;
    const int chunk = blockIdx.x & 7;
    const int t = threadIdx.x;
    const int d = t & 63, sg = t >> 6;
    const float* qh = q + (size_t)head * SD;
    const int s0 = chunk * 256;
    float acc = 0.f;
#pragma unroll 8
    for (int i = 0; i < 64; ++i) {
        int s = s0 + sg + 4 * i;
        acc += __expf(qh[s * Dh + d]);
    }
    __shared__ float part[4][64];
    part[sg][d] = acc;
    __syncthreads();
    if (sg == 0)
        atomicAdd(&qsum[head * 64 + d], part[0][d] + part[1][d] + part[2][d] + part[3][d]);
}

// ---- Qs = exp(q)/colsum -> bf16 ------------------------------------------
__global__ void k_qnorm(const float* __restrict__ q, const float* __restrict__ qsum,
                        ushort* __restrict__ Qs) {
    const int gid = blockIdx.x * 256 + threadIdx.x;
    const int i0 = gid * 8;
    const int head = i0 >> 17;
    const int d0 = i0 & 63;
    const float4 a = ((const float4*)(q + i0))[0];
    const float4 b = ((const float4*)(q + i0))[1];
    const float* qs = qsum + head * 64 + d0;
    s16x8 o;
    o[0] = (short)f2bf(__expf(a.x) / qs[0]);
    o[1] = (short)f2bf(__expf(a.y) / qs[1]);
    o[2] = (short)f2bf(__expf(a.z) / qs[2]);
    o[3] = (short)f2bf(__expf(a.w) / qs[3]);
    o[4] = (short)f2bf(__expf(b.x) / qs[4]);
    o[5] = (short)f2bf(__expf(b.y) / qs[5]);
    o[6] = (short)f2bf(__expf(b.z) / qs[6]);
    o[7] = (short)f2bf(__expf(b.w) / qs[7]);
    *(s16x8*)(Qs + i0) = o;
}

// ---- K softmax over heads axis (8 values) -> bf16 ------------------------
__global__ void k_ksoft(const float* __restrict__ kin, ushort* __restrict__ Ks) {
    const int gid = blockIdx.x * 256 + threadIdx.x;
    const int n = gid >> 17;
    const int rem = gid & (SD - 1);
    const float* base = kin + (size_t)n * 8 * SD + rem;
    float x[8];
    float sum = 0.f;
#pragma unroll
    for (int h = 0; h < 8; ++h) { x[h] = __expf(base[(size_t)h * SD]); sum += x[h]; }
    const float inv = 1.f / sum;
    ushort* ob = Ks + (size_t)n * 8 * SD + rem;
#pragma unroll
    for (int h = 0; h < 8; ++h) ob[(size_t)h * SD] = f2bf(x[h] * inv);
}

// ---- V transpose per head: [k][d] f32 -> Vt[d][k] bf16 -------------------
__global__ void k_vt(const float* __restrict__ V, ushort* __restrict__ Vt) {
    const int head = blockIdx.x >> 5, kt = blockIdx.x & 31;
    const int t = threadIdx.x;
    __shared__ float sv[64 * 68];
    const float4* src = (const float4*)(V + (size_t)head * SD + (size_t)kt * 64 * 64);
#pragma unroll
    for (int i = 0; i < 4; ++i) {
        int idx = t + 256 * i;
        int row = idx >> 4, c4 = idx & 15;
        *(float4*)&sv[row * 68 + c4 * 4] = src[idx];
    }
    __syncthreads();
    const int d = t >> 2, seg = t & 3;
    s16x8 v0, v1;
#pragma unroll
    for (int j = 0; j < 8; ++j) v0[j] = (short)f2bf(sv[(seg * 16 + j) * 68 + d]);
#pragma unroll
    for (int j = 0; j < 8; ++j) v1[j] = (short)f2bf(sv[(seg * 16 + 8 + j) * 68 + d]);
    ushort* dst = Vt + (size_t)head * SD + (size_t)d * S + kt * 64 + seg * 16;
    *(s16x8*)dst = v0;
    *(s16x8*)(dst + 8) = v1;
}

// ---- mask int32 [S][S] -> bitmask uint64[S][32] --------------------------
__global__ void k_mask(const int* __restrict__ mask, unsigned long long* __restrict__ bm) {
    const int t = threadIdx.x;
    const int g = blockIdx.x * 4 + (t >> 6);
    const int lane = t & 63;
    for (int it = 0; it < 64; ++it) {
        int w = g * 64 + it;
        int m = mask[(size_t)w * 64 + lane];
        unsigned long long b = __ballot(m != 0);
        if (lane == 0) bm[w] = b;
    }
}

#define LB 72   // bf16 LDS row stride
#define LF 68   // f32 LDS row stride

// ---- pass A: rowsum + normalized ctx. grid (64 qtiles of 32, 16 heads) ---
__global__ __launch_bounds__(256, 4) void k_ctx(
        const ushort* __restrict__ Qs, const ushort* __restrict__ Ks,
        const ushort* __restrict__ Vt, const unsigned long long* __restrict__ bm,
        float* __restrict__ ctx, float* __restrict__ rinv) {
    const int qt = blockIdx.x, head = blockIdx.y;
    const int q0 = qt * 32;
    const int t = threadIdx.x;
    const int lane = t & 63, wv = t >> 6;
    const int lm = lane & 15, lg = lane >> 4;
    const int wm = wv & 1;       // row half (q rows 16*wm..)
    const int wn = wv >> 1;      // col half (cols 32*wn..)

    __shared__ __align__(16) char smem[28416];
    ushort* sQ = (ushort*)smem;                                   // [32][72]
    ushort* sK = (ushort*)(smem + 4608);                          // [64][72]
    ushort* sV = (ushort*)(smem + 13824);                         // [64][72]
    ushort* sP = (ushort*)(smem + 23040);                         // [32][72]
    unsigned long long* sM = (unsigned long long*)(smem + 27648); // [32]
    float* sRS = (float*)(smem + 27904);                          // [32][2]

    // Q tile (persistent): 256 x 16B
    {
        const s16x8* src = (const s16x8*)(Qs + (size_t)head * SD + (size_t)q0 * 64);
        int row = t >> 3, seg = t & 7;
        *(s16x8*)&sQ[row * LB + seg * 8] = src[t];
    }

    f32x4 o[2];
    o[0] = (f32x4){0.f, 0.f, 0.f, 0.f};
    o[1] = (f32x4){0.f, 0.f, 0.f, 0.f};
    float rs[4] = {0.f, 0.f, 0.f, 0.f};

    const ushort* Kbase = Ks + (size_t)head * SD;
    const ushort* Vbase = Vt + (size_t)head * SD;

    for (int kt = 0; kt < 32; ++kt) {
        const int k0 = kt * 64;
        __syncthreads();
#pragma unroll
        for (int i = 0; i < 2; ++i) {
            int idx = t + 256 * i;
            int row = idx >> 3, seg = idx & 7;
            *(s16x8*)&sK[row * LB + seg * 8] = *(const s16x8*)(Kbase + (size_t)(k0 + row) * 64 + seg * 8);
            *(s16x8*)&sV[row * LB + seg * 8] = *(const s16x8*)(Vbase + (size_t)row * S + k0 + seg * 8);
        }
        if (t < 32) sM[t] = bm[(size_t)(q0 + t) * 32 + kt];
        __syncthreads();

        // QK^T: this wave's C tiles: rows 16*wm, cols 16*(2*wn+j), j=0,1
        f32x4 sc[2];
        sc[0] = (f32x4){0.f, 0.f, 0.f, 0.f};
        sc[1] = (f32x4){0.f, 0.f, 0.f, 0.f};
#pragma unroll
        for (int h = 0; h < 2; ++h) {
            s16x8 aq = *(const s16x8*)&sQ[(16 * wm + lm) * LB + 32 * h + 8 * lg];
#pragma unroll
            for (int j = 0; j < 2; ++j) {
                s16x8 bk = *(const s16x8*)&sK[(16 * (2 * wn + j) + lm) * LB + 32 * h + 8 * lg];
                sc[j] = __builtin_amdgcn_mfma_f32_16x16x32_bf16(aq, bk, sc[j], 0, 0, 0);
            }
        }
#pragma unroll
        for (int r = 0; r < 4; ++r) {
            const int rowl = 16 * wm + 4 * lg + r;
            const unsigned long long m64 = sM[rowl];
            float rsum = 0.f;
#pragma unroll
            for (int j = 0; j < 2; ++j) {
                const int col = 16 * (2 * wn + j) + lm;
                float p = ((m64 >> col) & 1ULL) ? __expf(sc[j][r]) : 0.f;
                rsum += p;
                sP[rowl * LB + col] = f2bf(p);
            }
            rsum += __shfl_xor(rsum, 1);
            rsum += __shfl_xor(rsum, 2);
            rsum += __shfl_xor(rsum, 4);
            rsum += __shfl_xor(rsum, 8);
            rs[r] += rsum;
        }
        __syncthreads();

        // PV: C tiles rows 16*wm (q), cols 16*(2*wn+j) (d)
#pragma unroll
        for (int h = 0; h < 2; ++h) {
            s16x8 ap = *(const s16x8*)&sP[(16 * wm + lm) * LB + 32 * h + 8 * lg];
#pragma unroll
            for (int j = 0; j < 2; ++j) {
                s16x8 bv = *(const s16x8*)&sV[(16 * (2 * wn + j) + lm) * LB + 32 * h + 8 * lg];
                o[j] = __builtin_amdgcn_mfma_f32_16x16x32_bf16(ap, bv, o[j], 0, 0, 0);
            }
        }
    }

    // combine rowsums across the two col-half waves
    if (lm == 0) {
#pragma unroll
        for (int r = 0; r < 4; ++r)
            sRS[(16 * wm + 4 * lg + r) * 2 + wn] = rs[r];
    }
    __syncthreads();
    if (t < 32) {
        float inv = 1.f / (sRS[t * 2] + sRS[t * 2 + 1]);
        rinv[head * S + q0 + t] = inv;
        sRS[t * 2] = inv;          // reuse slot 0 as inv for ctx write
    }
    __syncthreads();

#pragma unroll
    for (int r = 0; r < 4; ++r) {
        const int rowl = 16 * wm + 4 * lg + r;
        const float inv = sRS[rowl * 2];
        float* cb = ctx + (size_t)head * SD + (size_t)(q0 + rowl) * 64;
#pragma unroll
        for (int j = 0; j < 2; ++j)
            cb[16 * (2 * wn + j) + lm] = o[j][r] * inv;
    }
}

// ---- pass B: recompute scores, write normalized A ------------------------
// grid (32 qtiles of 64, 16 heads, 4 k-strips of 512)
__global__ __launch_bounds__(256, 4) void k_awrite(
        const ushort* __restrict__ Qs, const ushort* __restrict__ Ks,
        const unsigned long long* __restrict__ bm, const float* __restrict__ rinv,
        float* __restrict__ A) {
    const int qt = blockIdx.x, head = blockIdx.y, kc = blockIdx.z;
    const int q0 = qt * 64;
    const int t = threadIdx.x;
    const int lane = t & 63, wv = t >> 6;
    const int lm = lane & 15, lg = lane >> 4;

    __shared__ __align__(16) char smem[36608];
    ushort* sQ = (ushort*)smem;                                   // [64][72]
    ushort* sK = (ushort*)(smem + 9216);                          // [64][72]
    float* sPf = (float*)(smem + 18432);                          // [64][68]
    unsigned long long* sM = (unsigned long long*)(smem + 35840); // [64]
    float* sI = (float*)(smem + 36352);                           // [64]

    {
        const s16x8* src = (const s16x8*)(Qs + (size_t)head * SD + (size_t)q0 * 64);
#pragma unroll
        for (int i = 0; i < 2; ++i) {
            int idx = t + 256 * i;
            int row = idx >> 3, seg = idx & 7;
            *(s16x8*)&sQ[row * LB + seg * 8] = src[idx];
        }
        if (t < 64) sI[t] = rinv[head * S + q0 + t];
    }

    const ushort* Kbase = Ks + (size_t)head * SD;
    float* Abase = A + (size_t)head * SSZ;

    for (int kt8 = 0; kt8 < 8; ++kt8) {
        const int k0 = kc * 512 + kt8 * 64;
        __syncthreads();
#pragma unroll
        for (int i = 0; i < 2; ++i) {
            int idx = t + 256 * i;
            int row = idx >> 3, seg = idx & 7;
            *(s16x8*)&sK[row * LB + seg * 8] = *(const s16x8*)(Kbase + (size_t)(k0 + row) * 64 + seg * 8);
        }
        if (t < 64) sM[t] = bm[(size_t)(q0 + t) * 32 + (k0 >> 6)];
        __syncthreads();

        f32x4 sc[4];
#pragma unroll
        for (int c = 0; c < 4; ++c) sc[c] = (f32x4){0.f, 0.f, 0.f, 0.f};
#pragma unroll
        for (int h = 0; h < 2; ++h) {
            s16x8 aq = *(const s16x8*)&sQ[(16 * wv + lm) * LB + 32 * h + 8 * lg];
#pragma unroll
            for (int c = 0; c < 4; ++c) {
                s16x8 bk = *(const s16x8*)&sK[(16 * c + lm) * LB + 32 * h + 8 * lg];
                sc[c] = __builtin_amdgcn_mfma_f32_16x16x32_bf16(aq, bk, sc[c], 0, 0, 0);
            }
        }
#pragma unroll
        for (int r = 0; r < 4; ++r) {
            const int rowl = 16 * wv + 4 * lg + r;
            const unsigned long long m64 = sM[rowl];
            const float invr = sI[rowl];
#pragma unroll
            for (int c = 0; c < 4; ++c) {
                const int col = 16 * c + lm;
                sPf[rowl * LF + col] = ((m64 >> col) & 1ULL) ? __expf(sc[c][r]) * invr : 0.f;
            }
        }
        __syncthreads();
#pragma unroll
        for (int i = 0; i < 4; ++i) {
            int idx = t + 256 * i;
            int row = idx >> 4, c4 = idx & 15;
            *(float4*)&Abase[(size_t)(q0 + row) * S + k0 + c4 * 4] = *(const float4*)&sPf[row * LF + c4 * 4];
        }
    }
}

extern "C" void kernel_launch(void* const* d_in, const int* in_sizes, int n_in,
                              void* d_out, int out_size, void* d_ws, size_t ws_size,
                              hipStream_t stream) {
    const float* q = (const float*)d_in[0];
    const float* k = (const float*)d_in[1];
    const float* v = (const float*)d_in[2];
    const int* mask = (const int*)d_in[3];
    float* out = (float*)d_out;   // [0, NH*SD) ctx ; [NH*SD, +NH*S*S) attn weights
    char* ws = (char*)d_ws;

    float* qsum = (float*)(ws + WSB_QSUM);
    float* rinv = (float*)(ws + WSB_RINV);
    unsigned long long* bm = (unsigned long long*)(ws + WSB_MASK);
    ushort* Qs = (ushort*)(ws + WSB_QS);
    ushort* Ks = (ushort*)(ws + WSB_KS);
    ushort* Vt = (ushort*)(ws + WSB_VT);

    hipMemsetAsync(d_ws, 0, 4096, stream);
    k_qsum<<<128, 256, 0, stream>>>(q, qsum);
    k_mask<<<256, 256, 0, stream>>>(mask, bm);
    k_qnorm<<<1024, 256, 0, stream>>>(q, qsum, Qs);
    k_ksoft<<<1024, 256, 0, stream>>>(k, Ks);
    k_vt<<<512, 256, 0, stream>>>(v, Vt);
    k_ctx<<<dim3(64, 16), 256, 0, stream>>>(Qs, Ks, Vt, bm, out, rinv);
    k_awrite<<<dim3(32, 16, 4), 256, 0, stream>>>(Qs, Ks, bm, rinv, out + (size_t)NH * SD);
}

// Round 5
// 406.948 us; speedup vs baseline: 1.0599x; 1.0599x over previous
//
#include <hip/hip_runtime.h>

#define S 2048
#define Dh 64
#define NH 16
#define SD (S*Dh)                 // 131072 elements per head plane
#define SSZ ((size_t)S*(size_t)S) // attention matrix elements per head

typedef __attribute__((ext_vector_type(4))) float f32x4;
typedef __attribute__((ext_vector_type(8))) short s16x8;

// workspace layout (byte offsets)
#define WSB_QSUM 0                          // 1024 f32 (4 KB)
#define WSB_RINV 4096                       // 16*2048 f32 (128 KB)
#define WSB_MASK 135168                     // 65536 uint64 bitmask (512 KB)
#define WSB_QS   659456                     // NH*SD bf16 (4 MB)
#define WSB_KS   (WSB_QS + 4194304)
#define WSB_VT   (WSB_KS + 4194304)         // ends ~12.6 MB

__device__ __forceinline__ ushort f2bf(float x) {
    unsigned u = __builtin_bit_cast(unsigned, x);
    u = (u + 0x7fffu + ((u >> 16) & 1u)) >> 16;
    return (ushort)u;
}

// ---- Q column-softmax denominators: sum_s exp(q[h,s,d]) per (head,d) ------
__global__ void k_qsum(const float* __restrict__ q, float* __restrict__ qsum) {
    const int head  = blockIdx.x >> 5;
    const int chunk = blockIdx.x & 31;       // 64 s-values per chunk
    const int t = threadIdx.x;
    const int d = t & 63, sg = t >> 6;
    const float* qh = q + (size_t)head * SD;
    const int s0 = chunk * 64;
    float acc = 0.f;
#pragma unroll
    for (int i = 0; i < 16; ++i) {
        int s = s0 + sg + 4 * i;
        acc += __expf(qh[s * Dh + d]);
    }
    __shared__ float part[4][64];
    part[sg][d] = acc;
    __syncthreads();
    if (sg == 0)
        atomicAdd(&qsum[head * 64 + d], part[0][d] + part[1][d] + part[2][d] + part[3][d]);
}

// ---- Qs = exp(q)/colsum -> bf16 ------------------------------------------
__global__ void k_qnorm(const float* __restrict__ q, const float* __restrict__ qsum,
                        ushort* __restrict__ Qs) {
    const int gid = blockIdx.x * 256 + threadIdx.x;
    const int i0 = gid * 8;
    const int head = i0 >> 17;
    const int d0 = i0 & 63;
    const float4 a = ((const float4*)(q + i0))[0];
    const float4 b = ((const float4*)(q + i0))[1];
    const float* qs = qsum + head * 64 + d0;
    s16x8 o;
    o[0] = (short)f2bf(__expf(a.x) / qs[0]);
    o[1] = (short)f2bf(__expf(a.y) / qs[1]);
    o[2] = (short)f2bf(__expf(a.z) / qs[2]);
    o[3] = (short)f2bf(__expf(a.w) / qs[3]);
    o[4] = (short)f2bf(__expf(b.x) / qs[4]);
    o[5] = (short)f2bf(__expf(b.y) / qs[5]);
    o[6] = (short)f2bf(__expf(b.z) / qs[6]);
    o[7] = (short)f2bf(__expf(b.w) / qs[7]);
    *(s16x8*)(Qs + i0) = o;
}

// ---- K softmax over heads axis (8 values) -> bf16 ------------------------
__global__ void k_ksoft(const float* __restrict__ kin, ushort* __restrict__ Ks) {
    const int gid = blockIdx.x * 256 + threadIdx.x;
    const int n = gid >> 17;
    const int rem = gid & (SD - 1);
    const float* base = kin + (size_t)n * 8 * SD + rem;
    float x[8];
    float sum = 0.f;
#pragma unroll
    for (int h = 0; h < 8; ++h) { x[h] = __expf(base[(size_t)h * SD]); sum += x[h]; }
    const float inv = 1.f / sum;
    ushort* ob = Ks + (size_t)n * 8 * SD + rem;
#pragma unroll
    for (int h = 0; h < 8; ++h) ob[(size_t)h * SD] = f2bf(x[h] * inv);
}

// ---- V transpose per head: [k][d] f32 -> Vt[d][k] bf16 -------------------
__global__ void k_vt(const float* __restrict__ V, ushort* __restrict__ Vt) {
    const int head = blockIdx.x >> 5, kt = blockIdx.x & 31;
    const int t = threadIdx.x;
    __shared__ float sv[64 * 68];
    const float4* src = (const float4*)(V + (size_t)head * SD + (size_t)kt * 64 * 64);
#pragma unroll
    for (int i = 0; i < 4; ++i) {
        int idx = t + 256 * i;
        int row = idx >> 4, c4 = idx & 15;
        *(float4*)&sv[row * 68 + c4 * 4] = src[idx];
    }
    __syncthreads();
    const int d = t >> 2, seg = t & 3;
    s16x8 v0, v1;
#pragma unroll
    for (int j = 0; j < 8; ++j) v0[j] = (short)f2bf(sv[(seg * 16 + j) * 68 + d]);
#pragma unroll
    for (int j = 0; j < 8; ++j) v1[j] = (short)f2bf(sv[(seg * 16 + 8 + j) * 68 + d]);
    ushort* dst = Vt + (size_t)head * SD + (size_t)d * S + kt * 64 + seg * 16;
    *(s16x8*)dst = v0;
    *(s16x8*)(dst + 8) = v1;
}

// ---- mask int32 [S][S] -> bitmask uint64[S][32] --------------------------
__global__ void k_mask(const int* __restrict__ mask, unsigned long long* __restrict__ bm) {
    const int t = threadIdx.x;
    const int g = blockIdx.x * 4 + (t >> 6);   // wave id 0..4095
    const int lane = t & 63;
#pragma unroll
    for (int it = 0; it < 16; ++it) {
        int w = g * 16 + it;
        int m = mask[(size_t)w * 64 + lane];
        unsigned long long b = __ballot(m != 0);
        if (lane == 0) bm[w] = b;
    }
}

#define LB 72   // bf16 LDS row stride
#define LF 68   // f32 LDS row stride

// ---- pass A: rowsum + normalized ctx. grid (16 heads, 64 qtiles of 32) ---
// head in blockIdx.x => linear block id % 8 == head % 8 => all blocks of a
// head land on one XCD; per-XCD working set = 2 heads of K+V = 1.5 MB (L2-fit)
__global__ __launch_bounds__(256, 4) void k_ctx(
        const ushort* __restrict__ Qs, const ushort* __restrict__ Ks,
        const ushort* __restrict__ Vt, const unsigned long long* __restrict__ bm,
        float* __restrict__ ctx, float* __restrict__ rinv) {
    const int head = blockIdx.x, qt = blockIdx.y;
    const int q0 = qt * 32;
    const int t = threadIdx.x;
    const int lane = t & 63, wv = t >> 6;
    const int lm = lane & 15, lg = lane >> 4;
    const int wm = wv & 1;       // row half (q rows 16*wm..)
    const int wn = wv >> 1;      // col half (cols 32*wn..)

    __shared__ __align__(16) char smem[28416];
    ushort* sQ = (ushort*)smem;                                   // [32][72]
    ushort* sK = (ushort*)(smem + 4608);                          // [64][72]
    ushort* sV = (ushort*)(smem + 13824);                         // [64][72]
    ushort* sP = (ushort*)(smem + 23040);                         // [32][72]
    unsigned long long* sM = (unsigned long long*)(smem + 27648); // [32]
    float* sRS = (float*)(smem + 27904);                          // [32][2]

    // Q tile (persistent): 256 x 16B
    {
        const s16x8* src = (const s16x8*)(Qs + (size_t)head * SD + (size_t)q0 * 64);
        int row = t >> 3, seg = t & 7;
        *(s16x8*)&sQ[row * LB + seg * 8] = src[t];
    }

    f32x4 o[2];
    o[0] = (f32x4){0.f, 0.f, 0.f, 0.f};
    o[1] = (f32x4){0.f, 0.f, 0.f, 0.f};
    float rs[4] = {0.f, 0.f, 0.f, 0.f};

    const ushort* Kbase = Ks + (size_t)head * SD;
    const ushort* Vbase = Vt + (size_t)head * SD;

    for (int kt = 0; kt < 32; ++kt) {
        const int k0 = kt * 64;
        __syncthreads();
#pragma unroll
        for (int i = 0; i < 2; ++i) {
            int idx = t + 256 * i;
            int row = idx >> 3, seg = idx & 7;
            *(s16x8*)&sK[row * LB + seg * 8] = *(const s16x8*)(Kbase + (size_t)(k0 + row) * 64 + seg * 8);
            *(s16x8*)&sV[row * LB + seg * 8] = *(const s16x8*)(Vbase + (size_t)row * S + k0 + seg * 8);
        }
        if (t < 32) sM[t] = bm[(size_t)(q0 + t) * 32 + kt];
        __syncthreads();

        f32x4 sc[2];
        sc[0] = (f32x4){0.f, 0.f, 0.f, 0.f};
        sc[1] = (f32x4){0.f, 0.f, 0.f, 0.f};
#pragma unroll
        for (int h = 0; h < 2; ++h) {
            s16x8 aq = *(const s16x8*)&sQ[(16 * wm + lm) * LB + 32 * h + 8 * lg];
#pragma unroll
            for (int j = 0; j < 2; ++j) {
                s16x8 bk = *(const s16x8*)&sK[(16 * (2 * wn + j) + lm) * LB + 32 * h + 8 * lg];
                sc[j] = __builtin_amdgcn_mfma_f32_16x16x32_bf16(aq, bk, sc[j], 0, 0, 0);
            }
        }
#pragma unroll
        for (int r = 0; r < 4; ++r) {
            const int rowl = 16 * wm + 4 * lg + r;
            const unsigned long long m64 = sM[rowl];
            float rsum = 0.f;
#pragma unroll
            for (int j = 0; j < 2; ++j) {
                const int col = 16 * (2 * wn + j) + lm;
                float p = ((m64 >> col) & 1ULL) ? __expf(sc[j][r]) : 0.f;
                rsum += p;
                sP[rowl * LB + col] = f2bf(p);
            }
            rsum += __shfl_xor(rsum, 1);
            rsum += __shfl_xor(rsum, 2);
            rsum += __shfl_xor(rsum, 4);
            rsum += __shfl_xor(rsum, 8);
            rs[r] += rsum;
        }
        __syncthreads();

#pragma unroll
        for (int h = 0; h < 2; ++h) {
            s16x8 ap = *(const s16x8*)&sP[(16 * wm + lm) * LB + 32 * h + 8 * lg];
#pragma unroll
            for (int j = 0; j < 2; ++j) {
                s16x8 bv = *(const s16x8*)&sV[(16 * (2 * wn + j) + lm) * LB + 32 * h + 8 * lg];
                o[j] = __builtin_amdgcn_mfma_f32_16x16x32_bf16(ap, bv, o[j], 0, 0, 0);
            }
        }
    }

    if (lm == 0) {
#pragma unroll
        for (int r = 0; r < 4; ++r)
            sRS[(16 * wm + 4 * lg + r) * 2 + wn] = rs[r];
    }
    __syncthreads();
    if (t < 32) {
        float inv = 1.f / (sRS[t * 2] + sRS[t * 2 + 1]);
        rinv[head * S + q0 + t] = inv;
        sRS[t * 2] = inv;
    }
    __syncthreads();

#pragma unroll
    for (int r = 0; r < 4; ++r) {
        const int rowl = 16 * wm + 4 * lg + r;
        const float inv = sRS[rowl * 2];
        float* cb = ctx + (size_t)head * SD + (size_t)(q0 + rowl) * 64;
#pragma unroll
        for (int j = 0; j < 2; ++j)
            cb[16 * (2 * wn + j) + lm] = o[j][r] * inv;
    }
}

// ---- pass B: recompute scores, write normalized A ------------------------
// grid (16 heads, 32 qtiles of 64, 4 k-strips of 512); head on blockIdx.x
// for XCD locality of Ks; A stores are nontemporal to keep K resident in L2.
__global__ __launch_bounds__(256, 4) void k_awrite(
        const ushort* __restrict__ Qs, const ushort* __restrict__ Ks,
        const unsigned long long* __restrict__ bm, const float* __restrict__ rinv,
        float* __restrict__ A) {
    const int head = blockIdx.x, qt = blockIdx.y, kc = blockIdx.z;
    const int q0 = qt * 64;
    const int t = threadIdx.x;
    const int lane = t & 63, wv = t >> 6;
    const int lm = lane & 15, lg = lane >> 4;

    __shared__ __align__(16) char smem[36608];
    ushort* sQ = (ushort*)smem;                                   // [64][72]
    ushort* sK = (ushort*)(smem + 9216);                          // [64][72]
    float* sPf = (float*)(smem + 18432);                          // [64][68]
    unsigned long long* sM = (unsigned long long*)(smem + 35840); // [64]
    float* sI = (float*)(smem + 36352);                           // [64]

    {
        const s16x8* src = (const s16x8*)(Qs + (size_t)head * SD + (size_t)q0 * 64);
#pragma unroll
        for (int i = 0; i < 2; ++i) {
            int idx = t + 256 * i;
            int row = idx >> 3, seg = idx & 7;
            *(s16x8*)&sQ[row * LB + seg * 8] = src[idx];
        }
        if (t < 64) sI[t] = rinv[head * S + q0 + t];
    }

    const ushort* Kbase = Ks + (size_t)head * SD;
    float* Abase = A + (size_t)head * SSZ;

    for (int kt8 = 0; kt8 < 8; ++kt8) {
        const int k0 = kc * 512 + kt8 * 64;
        __syncthreads();
#pragma unroll
        for (int i = 0; i < 2; ++i) {
            int idx = t + 256 * i;
            int row = idx >> 3, seg = idx & 7;
            *(s16x8*)&sK[row * LB + seg * 8] = *(const s16x8*)(Kbase + (size_t)(k0 + row) * 64 + seg * 8);
        }
        if (t < 64) sM[t] = bm[(size_t)(q0 + t) * 32 + (k0 >> 6)];
        __syncthreads();

        f32x4 sc[4];
#pragma unroll
        for (int c = 0; c < 4; ++c) sc[c] = (f32x4){0.f, 0.f, 0.f, 0.f};
#pragma unroll
        for (int h = 0; h < 2; ++h) {
            s16x8 aq = *(const s16x8*)&sQ[(16 * wv + lm) * LB + 32 * h + 8 * lg];
#pragma unroll
            for (int c = 0; c < 4; ++c) {
                s16x8 bk = *(const s16x8*)&sK[(16 * c + lm) * LB + 32 * h + 8 * lg];
                sc[c] = __builtin_amdgcn_mfma_f32_16x16x32_bf16(aq, bk, sc[c], 0, 0, 0);
            }
        }
#pragma unroll
        for (int r = 0; r < 4; ++r) {
            const int rowl = 16 * wv + 4 * lg + r;
            const unsigned long long m64 = sM[rowl];
            const float invr = sI[rowl];
#pragma unroll
            for (int c = 0; c < 4; ++c) {
                const int col = 16 * c + lm;
                sPf[rowl * LF + col] = ((m64 >> col) & 1ULL) ? __expf(sc[c][r]) * invr : 0.f;
            }
        }
        __syncthreads();
#pragma unroll
        for (int i = 0; i < 4; ++i) {
            int idx = t + 256 * i;
            int row = idx >> 4, c4 = idx & 15;
            __builtin_nontemporal_store(
                *(const f32x4*)&sPf[row * LF + c4 * 4],
                (f32x4*)&Abase[(size_t)(q0 + row) * S + k0 + c4 * 4]);
        }
    }
}

extern "C" void kernel_launch(void* const* d_in, const int* in_sizes, int n_in,
                              void* d_out, int out_size, void* d_ws, size_t ws_size,
                              hipStream_t stream) {
    const float* q = (const float*)d_in[0];
    const float* k = (const float*)d_in[1];
    const float* v = (const float*)d_in[2];
    const int* mask = (const int*)d_in[3];
    float* out = (float*)d_out;   // [0, NH*SD) ctx ; [NH*SD, +NH*S*S) attn weights
    char* ws = (char*)d_ws;

    float* qsum = (float*)(ws + WSB_QSUM);
    float* rinv = (float*)(ws + WSB_RINV);
    unsigned long long* bm = (unsigned long long*)(ws + WSB_MASK);
    ushort* Qs = (ushort*)(ws + WSB_QS);
    ushort* Ks = (ushort*)(ws + WSB_KS);
    ushort* Vt = (ushort*)(ws + WSB_VT);

    (void)hipMemsetAsync(d_ws, 0, 4096, stream);
    k_qsum<<<512, 256, 0, stream>>>(q, qsum);
    k_mask<<<1024, 256, 0, stream>>>(mask, bm);
    k_qnorm<<<1024, 256, 0, stream>>>(q, qsum, Qs);
    k_ksoft<<<1024, 256, 0, stream>>>(k, Ks);
    k_vt<<<512, 256, 0, stream>>>(v, Vt);
    k_ctx<<<dim3(16, 64), 256, 0, stream>>>(Qs, Ks, Vt, bm, out, rinv);
    k_awrite<<<dim3(16, 32, 4), 256, 0, stream>>>(Qs, Ks, bm, rinv, out + (size_t)NH * SD);
}